// Round 10
// baseline (4357.832 us; speedup 1.0000x reference)
//
#include <hip/hip_runtime.h>
#include <math.h>

static constexpr int TT = 1024, BB = 64, DHID = 256, NLAY = 8, OSL = 24;
static constexpr int T0H = 192, THN = 832;   // h panels cover t in [192,1024)
static constexpr int T0G = 256, TGN = 768;   // gated panels cover t in [256,1024)

typedef __attribute__((ext_vector_type(8))) short short8;   // 8 bf16
typedef __attribute__((ext_vector_type(4))) float f32x4;
typedef unsigned short u16;
typedef __attribute__((ext_vector_type(4))) unsigned short u16x4;
typedef unsigned int u32;

__device__ __forceinline__ u16 f2bf(float x) {
  u32 u = __float_as_uint(x);
  return (u16)((u + 0x7fffu + ((u >> 16) & 1u)) >> 16);   // RNE
}
__device__ __forceinline__ float bf2f(u16 v) {
  return __uint_as_float((u32)v << 16);
}

// ---------------------------------------------------------------------------
// Weight prep (R5 layouts):
//  wP  [l][tap][kc][cs:2][p:4][row:256][8]  row<128: f (o=cs*128+row) else g (+256)
//  swH [l][kc][p:4][o:256][8]               h-half of skip_w
//  swG [l][kc][p:4][o:256][8]               g-half
// ---------------------------------------------------------------------------
__global__ __launch_bounds__(256) void wprep(
    const float* __restrict__ cw, const float* __restrict__ sw,
    u16* __restrict__ wP, u16* __restrict__ swH, u16* __restrict__ swG)
{
  const int stride = gridDim.x * 256;
  for (int i = blockIdx.x * 256 + threadIdx.x; i < NLAY * 3 * 8 * 2 * 4 * 2048; i += stride) {
    const int e = i & 7, row = (i >> 3) & 255;
    int q = i >> 11;
    const int p = q & 3; q >>= 2;
    const int cs = q & 1; q >>= 1;
    const int kc = q & 7; q >>= 3;
    const int tap = q % 3, l = q / 3;
    const int o = (row < 128) ? (cs * 128 + row) : (256 + cs * 128 + (row - 128));
    const int c = kc * 32 + p * 8 + e;
    wP[i] = f2bf(cw[((size_t)(l * 512 + o) * 256 + c) * 3 + tap]);
  }
  for (int i = blockIdx.x * 256 + threadIdx.x; i < NLAY * 8 * 4 * 2048; i += stride) {
    const int e = i & 7, o = (i >> 3) & 255, p = (i >> 11) & 3, kc = (i >> 13) & 7, l = i >> 16;
    const int c = kc * 32 + p * 8 + e;
    swH[i] = f2bf(sw[(size_t)(l * 512 + o) * 256 + c]);
    swG[i] = f2bf(sw[(size_t)(l * 512 + 256 + o) * 256 + c]);
  }
}

// ---------------------------------------------------------------------------
// Up projection -> h bf16 panels [b][cpart:32][t-192][8], t in [192,1024).
// ---------------------------------------------------------------------------
__global__ __launch_bounds__(256) void up_kernel(
    const float* __restrict__ xlag, const float* __restrict__ xcov,
    const float* __restrict__ upw, const float* __restrict__ upb,
    u16* __restrict__ hb0)
{
  const int b  = blockIdx.y;
  const int t0 = T0H + blockIdx.x * 16;
  __shared__ float xs[16][17];
  {
    const int tl = threadIdx.x >> 4;
    const int j  = threadIdx.x & 15;
    const size_t base = ((size_t)(t0 + tl) * BB + b) * 8;
    xs[tl][j] = (j < 8) ? xlag[base + j] : xcov[base + (j - 8)];
  }
  __syncthreads();
  const int c = threadIdx.x;
  float uw[16];
#pragma unroll
  for (int j = 0; j < 16; ++j) uw[j] = upw[j * DHID + c];
  const float bias = upb[c];
#pragma unroll
  for (int tl = 0; tl < 16; ++tl) {
    float acc = bias;
#pragma unroll
    for (int j = 0; j < 16; ++j) acc = fmaf(xs[tl][j], uw[j], acc);
    hb0[(((size_t)b * 32 + (c >> 3)) * THN + (t0 + tl - T0H)) * 8 + (c & 7)] = f2bf(acc);
  }
}

// ---------------------------------------------------------------------------
// Conv+gate, BARRIER-FREE K-loop: each wave loads its MFMA fragments
// directly from global (panel layouts are frag-native: 256B contiguous per
// quad). Depth-1 register prefetch; no LDS staging, no __syncthreads in the
// K-loop. 1024 thr, M=256 (128f|128g of cs-half), N=256 (4 batches x 64 t),
// K=32/step, 24 steps. LDS only for the output transpose epilogue.
// ---------------------------------------------------------------------------
__global__ __launch_bounds__(1024, 8) void conv_gate(
    const u16* __restrict__ hbin, const u16* __restrict__ wPl,
    const float* __restrict__ cb, u16* __restrict__ gbuf,
    u16* __restrict__ g15l, const int dil, const int tile0)
{
  __shared__ u16 gT[32768];   // 64KB epilogue transpose
  const int tid = threadIdx.x, w = tid >> 6, lane = tid & 63;
  const int l16 = lane & 15, quad = lane >> 4;
  const int mw = w & 3, nw = w >> 2;
  const int tile = tile0 + (int)(blockIdx.x >> 4);
  const int b0 = (blockIdx.x & 15) * 4;
  const int cs = blockIdx.y;
  const int t0 = tile * 64;

  // frag-native base pointers
  const u16* aBase = wPl + (size_t)cs * 8192 + ((size_t)quad * 256 + l16) * 8;
  const u16* bBase = hbin + (((size_t)(b0 + nw) * 32 + quad) * THN + (t0 - T0H + l16)) * 8;

  auto loadAfr = [&](int step, int m) -> short8 {   // A frag: rows m-block, k=step
    const int row = (m < 2) ? (mw * 32 + 16 * m) : (128 + mw * 32 + 16 * (m - 2));
    return *(const short8*)(aBase + (size_t)step * 16384 + row * 8);
  };
  auto loadBfr = [&](int step, int j) -> short8 {   // B frag: t'=16j+l16, k=step
    const int tap = step >> 3, kc = step & 7;
    const int sh = (2 - tap) * dil;
    return *(const short8*)(bBase + ((size_t)(kc * 4) * THN + 16 * j - sh) * 8);
  };

  f32x4 acc[4][4];
  const f32x4 zero = {0.f, 0.f, 0.f, 0.f};
#pragma unroll
  for (int m = 0; m < 4; ++m)
#pragma unroll
    for (int j = 0; j < 4; ++j) acc[m][j] = zero;

  short8 aC[4], bC[4], aN[4], bN[4];
#pragma unroll
  for (int m = 0; m < 4; ++m) aC[m] = loadAfr(0, m);
#pragma unroll
  for (int j = 0; j < 4; ++j) bC[j] = loadBfr(0, j);

  for (int step = 0; step < 24; ++step) {
    const int ns = step + 1;
    if (ns < 24) {
#pragma unroll
      for (int m = 0; m < 4; ++m) aN[m] = loadAfr(ns, m);
#pragma unroll
      for (int j = 0; j < 4; ++j) bN[j] = loadBfr(ns, j);
    }
#pragma unroll
    for (int m = 0; m < 4; ++m)
#pragma unroll
      for (int j = 0; j < 4; ++j)
        acc[m][j] = __builtin_amdgcn_mfma_f32_16x16x32_bf16(aC[m], bC[j], acc[m][j], 0, 0, 0);
#pragma unroll
    for (int m = 0; m < 4; ++m) aC[m] = aN[m];
#pragma unroll
    for (int j = 0; j < 4; ++j) bC[j] = bN[j];
  }

  // gate in-register -> LDS transpose -> coalesced global store
#pragma unroll
  for (int m = 0; m < 2; ++m) {
    const int c4 = mw * 32 + 16 * m + quad * 4;   // local f row base (0..127)
    const int cpl = c4 >> 3;
#pragma unroll
    for (int j = 0; j < 4; ++j) {
      const int tl = 16 * j + l16;
      u16x4 pk;
#pragma unroll
      for (int r = 0; r < 4; ++r) {
        const float f = acc[m][j][r]     + cb[cs * 128 + c4 + r];
        const float g = acc[m + 2][j][r] + cb[256 + cs * 128 + c4 + r];
        const float th = 2.f / (1.f + __expf(-2.f * f)) - 1.f;
        const float sg = 1.f / (1.f + __expf(-g));
        pk[r] = f2bf(th * sg);
      }
      *(u16x4*)&gT[((nw * 16 + cpl) * 64 + tl) * 8 + (quad & 1) * 4] = pk;
    }
  }
  __syncthreads();
#pragma unroll
  for (int k = 0; k < 4; ++k) {
    const int slot = k * 1024 + tid;
    const int ct = slot >> 10, cpl = (slot >> 6) & 15, tl = slot & 63;
    const short8 v = *(const short8*)&gT[slot * 8];
    const int b = b0 + ct, cpg = cs * 16 + cpl;
    *(short8*)&gbuf[(((size_t)b * 32 + cpg) * TGN + (t0 + tl - T0G)) * 8] = v;
    if (tile == 15)
      *(short8*)&g15l[(((size_t)b * 32 + cpg) * 64 + tl) * 8] = v;
  }
}

// ---------------------------------------------------------------------------
// Skip h-half GEMM + residual, barrier-free K-loop (direct frags):
// 1024 thr, M=256, N=256, K=256 (8 steps). h_new = h_old + out + bias.
// ---------------------------------------------------------------------------
__global__ __launch_bounds__(1024, 8) void skip_h(
    const u16* __restrict__ gbuf, const u16* __restrict__ swHl,
    const float* __restrict__ sb, const u16* __restrict__ hbin,
    u16* __restrict__ hbout, const int tile0)
{
  __shared__ u16 sT[32768];   // 64KB epilogue (f32 transpose)
  const int tid = threadIdx.x, w = tid >> 6, lane = tid & 63;
  const int l16 = lane & 15, quad = lane >> 4;
  const int mw = w & 3, nw = w >> 2;
  const int tile = tile0 + (int)(blockIdx.x >> 4);
  const int b0 = (blockIdx.x & 15) * 4;
  const int t0 = tile * 64;

  const u16* aBase = swHl + ((size_t)quad * 256 + mw * 64 + l16) * 8;
  const u16* bBase = gbuf + (((size_t)(b0 + nw) * 32 + quad) * TGN + (t0 - T0G + l16)) * 8;

  auto loadAfr = [&](int kc, int m) -> short8 {
    return *(const short8*)(aBase + (size_t)kc * 8192 + 16 * m * 8);
  };
  auto loadBfr = [&](int kc, int j) -> short8 {
    return *(const short8*)(bBase + ((size_t)(kc * 4) * TGN + 16 * j) * 8);
  };

  f32x4 acc[4][4];
  const f32x4 zero = {0.f, 0.f, 0.f, 0.f};
#pragma unroll
  for (int m = 0; m < 4; ++m)
#pragma unroll
    for (int j = 0; j < 4; ++j) acc[m][j] = zero;

  short8 aC[4], bC[4], aN[4], bN[4];
#pragma unroll
  for (int m = 0; m < 4; ++m) aC[m] = loadAfr(0, m);
#pragma unroll
  for (int j = 0; j < 4; ++j) bC[j] = loadBfr(0, j);

  for (int step = 0; step < 8; ++step) {
    const int ns = step + 1;
    if (ns < 8) {
#pragma unroll
      for (int m = 0; m < 4; ++m) aN[m] = loadAfr(ns, m);
#pragma unroll
      for (int j = 0; j < 4; ++j) bN[j] = loadBfr(ns, j);
    }
#pragma unroll
    for (int m = 0; m < 4; ++m)
#pragma unroll
      for (int j = 0; j < 4; ++j)
        acc[m][j] = __builtin_amdgcn_mfma_f32_16x16x32_bf16(aC[m], bC[j], acc[m][j], 0, 0, 0);
#pragma unroll
    for (int m = 0; m < 4; ++m) aC[m] = aN[m];
#pragma unroll
    for (int j = 0; j < 4; ++j) bC[j] = bN[j];
  }

  // 4 ct-rounds: f32 transpose in LDS, then bf16 RMW (coalesced)
  float* fT = (float*)sT;   // [cpl:32][tl:64][8] f32
  for (int ctr = 0; ctr < 4; ++ctr) {
    __syncthreads();
    if (nw == ctr) {
#pragma unroll
      for (int m = 0; m < 4; ++m) {
        const int c4 = mw * 64 + 16 * m + quad * 4;
#pragma unroll
        for (int j = 0; j < 4; ++j) {
          const int tl = 16 * j + l16;
          f32x4 v;
#pragma unroll
          for (int r = 0; r < 4; ++r) v[r] = acc[m][j][r] + sb[c4 + r];
          *(f32x4*)&fT[((c4 >> 3) * 64 + tl) * 8 + (quad & 1) * 4] = v;
        }
      }
    }
    __syncthreads();
    const int b = b0 + ctr;
#pragma unroll
    for (int k = 0; k < 2; ++k) {
      const int slot = k * 1024 + tid;
      const int cpl = slot >> 6, tl = slot & 63;
      const size_t idx = (((size_t)b * 32 + cpl) * THN + (t0 - T0H + tl)) * 8;
      const short8 hv = *(const short8*)&hbin[idx];
      short8 ov;
#pragma unroll
      for (int e = 0; e < 8; ++e)
        ov[e] = (short)f2bf(bf2f((u16)hv[e]) + fT[slot * 8 + e]);
      *(short8*)&hbout[idx] = ov;
    }
  }
}

// ---------------------------------------------------------------------------
// Skip g-half partials, barrier-free: block (b, l): M=256, N=32, K=256.
// gpart[l][b][c][32] f32; head reduces over l.
// ---------------------------------------------------------------------------
__global__ __launch_bounds__(512) void skip_g(
    const u16* __restrict__ g15, const u16* __restrict__ swG,
    float* __restrict__ gpart)
{
  const int tid = threadIdx.x, w = tid >> 6, lane = tid & 63;
  const int l16 = lane & 15, quad = lane >> 4;
  const int b = blockIdx.x, l = blockIdx.y;

  const u16* aBase = swG + (size_t)l * 65536 + ((size_t)quad * 256 + w * 32 + l16) * 8;
  const u16* bBase = g15 + ((((size_t)l * 64 + b) * 32 + quad) * 64 + 32 + l16) * 8;

  auto loadAfr = [&](int kc, int m) -> short8 {
    return *(const short8*)(aBase + (size_t)kc * 8192 + 16 * m * 8);
  };
  auto loadBfr = [&](int kc, int j) -> short8 {
    return *(const short8*)(bBase + ((size_t)(kc * 4) * 64 + 16 * j) * 8);
  };

  f32x4 acc[2][2];
  const f32x4 zero = {0.f, 0.f, 0.f, 0.f};
#pragma unroll
  for (int m = 0; m < 2; ++m)
#pragma unroll
    for (int j = 0; j < 2; ++j) acc[m][j] = zero;

  short8 aC[2], bC[2], aN[2], bN[2];
#pragma unroll
  for (int m = 0; m < 2; ++m) aC[m] = loadAfr(0, m);
#pragma unroll
  for (int j = 0; j < 2; ++j) bC[j] = loadBfr(0, j);

  for (int step = 0; step < 8; ++step) {
    const int ns = step + 1;
    if (ns < 8) {
#pragma unroll
      for (int m = 0; m < 2; ++m) aN[m] = loadAfr(ns, m);
#pragma unroll
      for (int j = 0; j < 2; ++j) bN[j] = loadBfr(ns, j);
    }
#pragma unroll
    for (int m = 0; m < 2; ++m)
#pragma unroll
      for (int j = 0; j < 2; ++j)
        acc[m][j] = __builtin_amdgcn_mfma_f32_16x16x32_bf16(aC[m], bC[j], acc[m][j], 0, 0, 0);
#pragma unroll
    for (int m = 0; m < 2; ++m) aC[m] = aN[m];
#pragma unroll
    for (int j = 0; j < 2; ++j) bC[j] = bN[j];
  }
#pragma unroll
  for (int m = 0; m < 2; ++m)
#pragma unroll
    for (int j = 0; j < 2; ++j)
#pragma unroll
      for (int r = 0; r < 4; ++r) {
        const int c = w * 32 + 16 * m + quad * 4 + r;
        gpart[(((size_t)l * 64 + b) * 256 + c) * 32 + 16 * j + l16] = acc[m][j][r];
      }
}

// ---------------------------------------------------------------------------
// Head: reduce gpart over l, add g-biases, fc+relu, loc/scale.
// ---------------------------------------------------------------------------
__global__ __launch_bounds__(256) void head_kernel(
    const float* __restrict__ gpart, const float* __restrict__ skip_b,
    const float* __restrict__ fcw, const float* __restrict__ fcb,
    const float* __restrict__ locw, const float* __restrict__ locb,
    const float* __restrict__ scw, const float* __restrict__ scb,
    float* __restrict__ out)
{
  const int tt = blockIdx.x;
  const int b  = blockIdx.y;
  const int c  = threadIdx.x;
  __shared__ float xs[DHID];
  float s = 0.f;
#pragma unroll
  for (int l = 0; l < NLAY; ++l) {
    s += skip_b[l * 512 + 256 + c];
    s += gpart[(((size_t)l * 64 + b) * 256 + c) * 32 + (8 + tt)];
  }
  xs[c] = s;
  __syncthreads();
  float acc = fcb[c];
#pragma unroll 8
  for (int j = 0; j < DHID; ++j) acc = fmaf(xs[j], fcw[j * DHID + c], acc);
  const float ff = fmaxf(acc, 0.f);
  float pl = ff * locw[c];
  float ps = ff * scw[c];
#pragma unroll
  for (int off = 32; off > 0; off >>= 1) {
    pl += __shfl_down(pl, off);
    ps += __shfl_down(ps, off);
  }
  __shared__ float rl[4], rs[4];
  const int wid = threadIdx.x >> 6, lane = threadIdx.x & 63;
  if (lane == 0) { rl[wid] = pl; rs[wid] = ps; }
  __syncthreads();
  if (threadIdx.x == 0) {
    const float loc = rl[0] + rl[1] + rl[2] + rl[3] + locb[0];
    const float x   = rs[0] + rs[1] + rs[2] + rs[3] + scb[0];
    const float sp  = (x > 0.f) ? (x + log1pf(expf(-x))) : log1pf(expf(x));
    out[2 + tt * BB + b]            = loc;
    out[2 + OSL * BB + tt * BB + b] = sp + 1e-6f;
  }
}

__global__ __launch_bounds__(256) void loss_kernel(
    const float* __restrict__ y, float* __restrict__ out)
{
  float s = 0.f;
  for (int i = threadIdx.x; i < OSL * BB; i += 256) {
    const int tt = i >> 6, b = i & 63;
    const float loc = out[2 + i];
    const float sc  = out[2 + OSL * BB + i];
    const float yt  = y[(size_t)(TT - OSL + tt) * BB + b];
    const float z   = (yt - loc) / sc;
    s += -0.5f * z * z - logf(sc) - 0.9189385332046727f;
  }
#pragma unroll
  for (int off = 32; off > 0; off >>= 1) s += __shfl_down(s, off);
  __shared__ float r[4];
  if ((threadIdx.x & 63) == 0) r[threadIdx.x >> 6] = s;
  __syncthreads();
  if (threadIdx.x == 0) {
    const float loss = -(r[0] + r[1] + r[2] + r[3]) / (float)(OSL * BB);
    out[0] = loss;
    out[1] = loss;
  }
}

// ---------------------------------------------------------------------------
extern "C" void kernel_launch(void* const* d_in, const int* in_sizes, int n_in,
                              void* d_out, int out_size, void* d_ws, size_t ws_size,
                              hipStream_t stream) {
  (void)in_sizes; (void)n_in; (void)out_size; (void)ws_size;
  const float* X_cov  = (const float*)d_in[1];
  const float* X_lag  = (const float*)d_in[2];
  const float* y      = (const float*)d_in[3];
  const float* up_w   = (const float*)d_in[5];
  const float* up_b   = (const float*)d_in[6];
  const float* conv_w = (const float*)d_in[7];
  const float* conv_b = (const float*)d_in[8];
  const float* skip_w = (const float*)d_in[9];
  const float* skip_b = (const float*)d_in[10];
  const float* fc_w   = (const float*)d_in[11];
  const float* fc_b   = (const float*)d_in[12];
  const float* loc_w  = (const float*)d_in[13];
  const float* loc_b  = (const float*)d_in[14];
  const float* sc_w   = (const float*)d_in[15];
  const float* sc_b   = (const float*)d_in[16];

  // workspace layout (bytes), total ~122 MB
  char* wsb = (char*)d_ws;
  u16*   hb0   = (u16*)(wsb + 0);            // 27,262,976  [b][32][832][8]
  u16*   hb1   = (u16*)(wsb + 27262976);     // 27,262,976
  u16*   gbuf  = (u16*)(wsb + 54525952);     // 25,165,824  [b][32][768][8]
  u16*   g15   = (u16*)(wsb + 79691776);     // 16,777,216  [l][b][32][64][8]
  u16*   wP    = (u16*)(wsb + 96468992);     //  6,291,456
  u16*   swH   = (u16*)(wsb + 102760448);    //  1,048,576
  u16*   swG   = (u16*)(wsb + 103809024);    //  1,048,576
  float* gpart = (float*)(wsb + 104857600);  // 16,777,216  [l][b][256][32] f32

  wprep<<<1024, 256, 0, stream>>>(conv_w, skip_w, wP, swH, swG);
  up_kernel<<<dim3(52, BB), 256, 0, stream>>>(X_lag, X_cov, up_w, up_b, hb0);

  // minimal t-tiles per layer (receptive-field recurrence, tight at i=5,6,7)
  static const int Ptab[NLAY] = {4, 5, 6, 7, 8, 9, 11, 15};
  u16* hin = hb0;
  u16* hout = hb1;
  for (int i = 0; i < NLAY; ++i) {
    const int ntiles = 16 - Ptab[i];
    conv_gate<<<dim3(ntiles * 16, 2), 1024, 0, stream>>>(
        hin, wP + (size_t)i * 393216, conv_b + i * 512, gbuf,
        g15 + (size_t)i * 1048576, 1 << i, Ptab[i]);
    if (i < NLAY - 1) {   // layer 7's h-update is never consumed
      skip_h<<<dim3(ntiles * 16), 1024, 0, stream>>>(
          gbuf, swH + (size_t)i * 65536, skip_b + i * 512, hin, hout, Ptab[i]);
      u16* tmp = hin; hin = hout; hout = tmp;
    }
  }

  skip_g<<<dim3(64, 8), 512, 0, stream>>>(g15, swG, gpart);
  head_kernel<<<dim3(OSL, BB), 256, 0, stream>>>(
      gpart, skip_b, fc_w, fc_b, loc_w, loc_b, sc_w, sc_b, (float*)d_out);
  loss_kernel<<<1, 256, 0, stream>>>(y, (float*)d_out);
}

// Round 11
// 598.383 us; speedup vs baseline: 7.2827x; 7.2827x over previous
//
#include <hip/hip_runtime.h>
#include <math.h>

static constexpr int TT = 1024, BB = 64, DHID = 256, NLAY = 8, OSL = 24;
static constexpr int T0H = 192, THN = 832;   // h panels cover t in [192,1024)
static constexpr int T0G = 256, TGN = 768;   // gated panels cover t in [256,1024)

typedef __attribute__((ext_vector_type(8))) short short8;   // 8 bf16
typedef __attribute__((ext_vector_type(4))) float f32x4;
typedef unsigned short u16;
typedef __attribute__((ext_vector_type(4))) unsigned short u16x4;
typedef unsigned int u32;

__device__ __forceinline__ u16 f2bf(float x) {
  u32 u = __float_as_uint(x);
  return (u16)((u + 0x7fffu + ((u >> 16) & 1u)) >> 16);   // RNE
}
__device__ __forceinline__ float bf2f(u16 v) {
  return __uint_as_float((u32)v << 16);
}

// ---------------------------------------------------------------------------
// Weight prep (R5 layouts):
//  wP  [l][tap][kc][cs:2][p:4][row:256][8]  row<128: f (o=cs*128+row) else g (+256)
//  swH [l][kc][p:4][o:256][8]               h-half of skip_w
//  swG [l][kc][p:4][o:256][8]               g-half
// ---------------------------------------------------------------------------
__global__ __launch_bounds__(256) void wprep(
    const float* __restrict__ cw, const float* __restrict__ sw,
    u16* __restrict__ wP, u16* __restrict__ swH, u16* __restrict__ swG)
{
  const int stride = gridDim.x * 256;
  for (int i = blockIdx.x * 256 + threadIdx.x; i < NLAY * 3 * 8 * 2 * 4 * 2048; i += stride) {
    const int e = i & 7, row = (i >> 3) & 255;
    int q = i >> 11;
    const int p = q & 3; q >>= 2;
    const int cs = q & 1; q >>= 1;
    const int kc = q & 7; q >>= 3;
    const int tap = q % 3, l = q / 3;
    const int o = (row < 128) ? (cs * 128 + row) : (256 + cs * 128 + (row - 128));
    const int c = kc * 32 + p * 8 + e;
    wP[i] = f2bf(cw[((size_t)(l * 512 + o) * 256 + c) * 3 + tap]);
  }
  for (int i = blockIdx.x * 256 + threadIdx.x; i < NLAY * 8 * 4 * 2048; i += stride) {
    const int e = i & 7, o = (i >> 3) & 255, p = (i >> 11) & 3, kc = (i >> 13) & 7, l = i >> 16;
    const int c = kc * 32 + p * 8 + e;
    swH[i] = f2bf(sw[(size_t)(l * 512 + o) * 256 + c]);
    swG[i] = f2bf(sw[(size_t)(l * 512 + 256 + o) * 256 + c]);
  }
}

// ---------------------------------------------------------------------------
// Up projection -> h bf16 panels [b][cpart:32][t-192][8], t in [192,1024).
// ---------------------------------------------------------------------------
__global__ __launch_bounds__(256) void up_kernel(
    const float* __restrict__ xlag, const float* __restrict__ xcov,
    const float* __restrict__ upw, const float* __restrict__ upb,
    u16* __restrict__ hb0)
{
  const int b  = blockIdx.y;
  const int t0 = T0H + blockIdx.x * 16;
  __shared__ float xs[16][17];
  {
    const int tl = threadIdx.x >> 4;
    const int j  = threadIdx.x & 15;
    const size_t base = ((size_t)(t0 + tl) * BB + b) * 8;
    xs[tl][j] = (j < 8) ? xlag[base + j] : xcov[base + (j - 8)];
  }
  __syncthreads();
  const int c = threadIdx.x;
  float uw[16];
#pragma unroll
  for (int j = 0; j < 16; ++j) uw[j] = upw[j * DHID + c];
  const float bias = upb[c];
#pragma unroll
  for (int tl = 0; tl < 16; ++tl) {
    float acc = bias;
#pragma unroll
    for (int j = 0; j < 16; ++j) acc = fmaf(xs[tl][j], uw[j], acc);
    hb0[(((size_t)b * 32 + (c >> 3)) * THN + (t0 + tl - T0H)) * 8 + (c & 7)] = f2bf(acc);
  }
}

// ---------------------------------------------------------------------------
// Conv+gate: 512 thr (8 waves, 4mw x 2nw), M=256 (128f|128g of cs-half),
// N=128 (2 batches x 64 t), K=32/step, 24 steps. Pipelined LDS dbuf 48KB
// -> 2 blocks/CU resident (128 regs/wave). A prefetch depth-1 (L2-hot
// weights), B depth-2 (HBM/L2 latency covered across a barrier).
// ---------------------------------------------------------------------------
__global__ __launch_bounds__(512, 4) void conv_gate(
    const u16* __restrict__ hbin, const u16* __restrict__ wPl,
    const float* __restrict__ cb, u16* __restrict__ gbuf,
    u16* __restrict__ g15l, const int dil, const int tile0)
{
  __shared__ u16 AB[2][12288];   // per buf: A slots 0..1023 (16KB), B at +8192 (4KB)
  const int tid = threadIdx.x, w = tid >> 6, lane = tid & 63;
  const int l16 = lane & 15, quad = lane >> 4;
  const int mw = w & 3, nw = w >> 2;          // nw in 0..1
  const int tile = tile0 + (int)(blockIdx.x >> 5);
  const int b0 = (blockIdx.x & 31) * 2;
  const int cs = blockIdx.y;
  const int t0 = tile * 64;

  const int ctb = tid >> 8, pb = (tid >> 6) & 3, tlb = tid & 63;   // B slot decomp

  const u16* wBase = wPl + (size_t)cs * 8192 + tid * 8;   // thread owns A slots tid, tid+512
  const u16* hBase = hbin + (((size_t)(b0 + ctb) * 32 + pb) * THN + (t0 - T0H + tlb)) * 8;

  auto loadA0 = [&](int step) -> short8 {
    return *(const short8*)(wBase + (size_t)step * 16384);
  };
  auto loadA1 = [&](int step) -> short8 {
    return *(const short8*)(wBase + (size_t)step * 16384 + 4096);
  };
  auto loadB = [&](int step) -> short8 {
    const int tap = step >> 3, kc = step & 7;
    const int sh = (2 - tap) * dil;
    return *(const short8*)(hBase + ((size_t)(kc * 4) * THN - sh) * 8);
  };

  f32x4 acc[4][4];
  const f32x4 zero = {0.f, 0.f, 0.f, 0.f};
#pragma unroll
  for (int m = 0; m < 4; ++m)
#pragma unroll
    for (int j = 0; j < 4; ++j) acc[m][j] = zero;

  short8 vbN, vbF;
  {   // prologue: stage step 0; issue B(1)
    short8 a0 = loadA0(0), a1 = loadA1(0);
    short8 b  = loadB(0);
    *(short8*)&AB[0][(size_t)tid * 8] = a0;
    *(short8*)&AB[0][(size_t)(512 + tid) * 8] = a1;
    *(short8*)&AB[0][8192 + (size_t)tid * 8] = b;
    vbN = loadB(1);
  }
  __syncthreads();

  for (int step = 0; step < 24; ++step) {
    const int ns = step + 1;
    short8 vaN0, vaN1;
    if (ns < 24) {
      vaN0 = loadA0(ns); vaN1 = loadA1(ns);       // depth-1 (L2-hot)
      if (ns + 1 < 24) vbF = loadB(ns + 1);       // depth-2
    }
    const u16* A = AB[step & 1];
    const u16* B = AB[step & 1] + 8192;
    short8 bfr[4];
#pragma unroll
    for (int j = 0; j < 4; ++j)
      bfr[j] = *(const short8*)&B[(nw * 256 + quad * 64 + 16 * j + l16) * 8];
#pragma unroll
    for (int m = 0; m < 4; ++m) {
      const int row = (m < 2) ? (mw * 32 + 16 * m) : (128 + mw * 32 + 16 * (m - 2));
      const short8 a = *(const short8*)&A[(quad * 256 + row + l16) * 8];
#pragma unroll
      for (int j = 0; j < 4; ++j)
        acc[m][j] = __builtin_amdgcn_mfma_f32_16x16x32_bf16(a, bfr[j], acc[m][j], 0, 0, 0);
    }
    if (ns < 24) {
      *(short8*)&AB[ns & 1][(size_t)tid * 8] = vaN0;
      *(short8*)&AB[ns & 1][(size_t)(512 + tid) * 8] = vaN1;
      *(short8*)&AB[ns & 1][8192 + (size_t)tid * 8] = vbN;
      vbN = vbF;
    }
    __syncthreads();
  }

  // gate in-register -> LDS transpose (aliases AB, 32KB) -> coalesced store
  u16* gT = (u16*)AB;   // [ct:2][cpl:16][tl:64][8]
#pragma unroll
  for (int m = 0; m < 2; ++m) {
    const int c4 = mw * 32 + 16 * m + quad * 4;   // local f row base (0..127)
    const int cpl = c4 >> 3;
#pragma unroll
    for (int j = 0; j < 4; ++j) {
      const int tl = 16 * j + l16;
      u16x4 pk;
#pragma unroll
      for (int r = 0; r < 4; ++r) {
        const float f = acc[m][j][r]     + cb[cs * 128 + c4 + r];
        const float g = acc[m + 2][j][r] + cb[256 + cs * 128 + c4 + r];
        const float th = 2.f / (1.f + __expf(-2.f * f)) - 1.f;
        const float sg = 1.f / (1.f + __expf(-g));
        pk[r] = f2bf(th * sg);
      }
      *(u16x4*)&gT[((nw * 16 + cpl) * 64 + tl) * 8 + (quad & 1) * 4] = pk;
    }
  }
  __syncthreads();
#pragma unroll
  for (int k = 0; k < 4; ++k) {
    const int slot = k * 512 + tid;
    const int ct = slot >> 10, cpl = (slot >> 6) & 15, tl = slot & 63;
    const short8 v = *(const short8*)&gT[slot * 8];
    const int b = b0 + ct, cpg = cs * 16 + cpl;
    *(short8*)&gbuf[(((size_t)b * 32 + cpg) * TGN + (t0 + tl - T0G)) * 8] = v;
    if (tile == 15)
      *(short8*)&g15l[(((size_t)b * 32 + cpg) * 64 + tl) * 8] = v;
  }
}

// ---------------------------------------------------------------------------
// Skip h-half GEMM + residual: 512 thr, M=256, N=128 (2 batches), K=256
// (8 steps), pipelined LDS dbuf 48KB. h_new = h_old + out + bias (bf16 RMW).
// ---------------------------------------------------------------------------
__global__ __launch_bounds__(512, 4) void skip_h(
    const u16* __restrict__ gbuf, const u16* __restrict__ swHl,
    const float* __restrict__ sb, const u16* __restrict__ hbin,
    u16* __restrict__ hbout, const int tile0)
{
  __shared__ u16 AB[2][12288];
  const int tid = threadIdx.x, w = tid >> 6, lane = tid & 63;
  const int l16 = lane & 15, quad = lane >> 4;
  const int mw = w & 3, nw = w >> 2;          // nw in 0..1
  const int tile = tile0 + (int)(blockIdx.x >> 5);
  const int b0 = (blockIdx.x & 31) * 2;
  const int t0 = tile * 64;

  const int ctb = tid >> 8, pb = (tid >> 6) & 3, tlb = tid & 63;

  const u16* aBase = swHl + tid * 8;
  const u16* bBase = gbuf + (((size_t)(b0 + ctb) * 32 + pb) * TGN + (t0 - T0G + tlb)) * 8;

  auto loadA0 = [&](int kc) -> short8 {
    return *(const short8*)(aBase + (size_t)kc * 8192);
  };
  auto loadA1 = [&](int kc) -> short8 {
    return *(const short8*)(aBase + (size_t)kc * 8192 + 4096);
  };
  auto loadB = [&](int kc) -> short8 {
    return *(const short8*)(bBase + (size_t)kc * 4 * TGN * 8);
  };

  f32x4 acc[4][4];
  const f32x4 zero = {0.f, 0.f, 0.f, 0.f};
#pragma unroll
  for (int m = 0; m < 4; ++m)
#pragma unroll
    for (int j = 0; j < 4; ++j) acc[m][j] = zero;

  short8 vbN, vbF;
  {
    short8 a0 = loadA0(0), a1 = loadA1(0);
    short8 b  = loadB(0);
    *(short8*)&AB[0][(size_t)tid * 8] = a0;
    *(short8*)&AB[0][(size_t)(512 + tid) * 8] = a1;
    *(short8*)&AB[0][8192 + (size_t)tid * 8] = b;
    vbN = loadB(1);
  }
  __syncthreads();

  for (int step = 0; step < 8; ++step) {
    const int ns = step + 1;
    short8 vaN0, vaN1;
    if (ns < 8) {
      vaN0 = loadA0(ns); vaN1 = loadA1(ns);
      if (ns + 1 < 8) vbF = loadB(ns + 1);
    }
    const u16* A = AB[step & 1];
    const u16* B = AB[step & 1] + 8192;
    short8 bfr[4];
#pragma unroll
    for (int j = 0; j < 4; ++j)
      bfr[j] = *(const short8*)&B[(nw * 256 + quad * 64 + 16 * j + l16) * 8];
#pragma unroll
    for (int m = 0; m < 4; ++m) {
      const short8 a = *(const short8*)&A[(quad * 256 + mw * 64 + 16 * m + l16) * 8];
#pragma unroll
      for (int j = 0; j < 4; ++j)
        acc[m][j] = __builtin_amdgcn_mfma_f32_16x16x32_bf16(a, bfr[j], acc[m][j], 0, 0, 0);
    }
    if (ns < 8) {
      *(short8*)&AB[ns & 1][(size_t)tid * 8] = vaN0;
      *(short8*)&AB[ns & 1][(size_t)(512 + tid) * 8] = vaN1;
      *(short8*)&AB[ns & 1][8192 + (size_t)tid * 8] = vbN;
      vbN = vbF;
    }
    __syncthreads();
  }

  // 4 sub-rounds: (ctr batch in 0..1) x (hh half of c): f32 LDS transpose
  // (32KB, aliases AB) then coalesced bf16 RMW.
  float* fT = (float*)AB;   // [cpl:16][tl:64][8] f32
  for (int ctr = 0; ctr < 2; ++ctr) {
    for (int hh = 0; hh < 2; ++hh) {
      __syncthreads();
      if (nw == ctr && (mw >> 1) == hh) {
#pragma unroll
        for (int m = 0; m < 4; ++m) {
          const int c4 = mw * 64 + 16 * m + quad * 4;
          const int rl = c4 & 127;
#pragma unroll
          for (int j = 0; j < 4; ++j) {
            const int tl = 16 * j + l16;
            f32x4 v;
#pragma unroll
            for (int r = 0; r < 4; ++r) v[r] = acc[m][j][r] + sb[c4 + r];
            *(f32x4*)&fT[((rl >> 3) * 64 + tl) * 8 + (quad & 1) * 4] = v;
          }
        }
      }
      __syncthreads();
      const int b = b0 + ctr;
#pragma unroll
      for (int k = 0; k < 2; ++k) {
        const int slot = k * 512 + tid;
        const int cpl = slot >> 6, tl = slot & 63;
        const size_t idx = (((size_t)b * 32 + hh * 16 + cpl) * THN + (t0 - T0H + tl)) * 8;
        const short8 hv = *(const short8*)&hbin[idx];
        short8 ov;
#pragma unroll
        for (int e = 0; e < 8; ++e)
          ov[e] = (short)f2bf(bf2f((u16)hv[e]) + fT[slot * 8 + e]);
        *(short8*)&hbout[idx] = ov;
      }
    }
  }
}

// ---------------------------------------------------------------------------
// Skip g-half partials: block (b, l): M=256, N=32 (t 992..1023), K=256.
// gpart[l][b][c][32] f32; head reduces over l. Depth-2 pipeline (R8).
// ---------------------------------------------------------------------------
__global__ __launch_bounds__(512) void skip_g(
    const u16* __restrict__ g15, const u16* __restrict__ swG,
    float* __restrict__ gpart)
{
  __shared__ u16 AB[2][9216];   // A slots 0..1023, B slots at +8192 (128)
  const int tid = threadIdx.x, w = tid >> 6, lane = tid & 63;
  const int l16 = lane & 15, quad = lane >> 4;
  const int b = blockIdx.x, l = blockIdx.y;

  const u16* aBase = swG + (size_t)l * 65536 + tid * 8;
  const int pB = tid >> 5, tlB = tid & 31;
  const u16* bBase = g15 + ((((size_t)l * 64 + b) * 32 + pB) * 64 + 32 + tlB) * 8;

  auto loadA = [&](int kc, int q) -> short8 {
    return *(const short8*)(aBase + (size_t)kc * 8192 + q * 4096);
  };
  auto loadB = [&](int kc) -> short8 {   // valid for tid<128
    return *(const short8*)(bBase + (size_t)kc * 4 * 64 * 8);
  };

  f32x4 acc[2][2];
  const f32x4 zero = {0.f, 0.f, 0.f, 0.f};
#pragma unroll
  for (int m = 0; m < 2; ++m)
#pragma unroll
    for (int j = 0; j < 2; ++j) acc[m][j] = zero;

  short8 a0N, a1N, vbN, a0F, a1F, vbF;
  {
    short8 a0 = loadA(0, 0), a1 = loadA(0, 1);
    *(short8*)&AB[0][(size_t)tid * 8] = a0;
    *(short8*)&AB[0][(size_t)(512 + tid) * 8] = a1;
    if (tid < 128) {
      short8 vb = loadB(0);
      *(short8*)&AB[0][8192 + (size_t)tid * 8] = vb;
    }
    a0N = loadA(1, 0); a1N = loadA(1, 1);
    if (tid < 128) vbN = loadB(1);
  }
  __syncthreads();

  for (int step = 0; step < 8; ++step) {
    const int n2 = step + 2;
    if (n2 < 8) {
      a0F = loadA(n2, 0); a1F = loadA(n2, 1);
      if (tid < 128) vbF = loadB(n2);
    }
    const u16* A = AB[step & 1];
    const u16* B = AB[step & 1] + 8192;
    short8 bfr[2];
#pragma unroll
    for (int j = 0; j < 2; ++j)
      bfr[j] = *(const short8*)&B[(quad * 32 + 16 * j + l16) * 8];
#pragma unroll
    for (int m = 0; m < 2; ++m) {
      const short8 a = *(const short8*)&A[(quad * 256 + w * 32 + 16 * m + l16) * 8];
#pragma unroll
      for (int j = 0; j < 2; ++j)
        acc[m][j] = __builtin_amdgcn_mfma_f32_16x16x32_bf16(a, bfr[j], acc[m][j], 0, 0, 0);
    }
    const int ns = step + 1;
    if (ns < 8) {
      *(short8*)&AB[ns & 1][(size_t)tid * 8] = a0N;
      *(short8*)&AB[ns & 1][(size_t)(512 + tid) * 8] = a1N;
      if (tid < 128) *(short8*)&AB[ns & 1][8192 + (size_t)tid * 8] = vbN;
    }
    a0N = a0F; a1N = a1F; vbN = vbF;
    __syncthreads();
  }
#pragma unroll
  for (int m = 0; m < 2; ++m)
#pragma unroll
    for (int j = 0; j < 2; ++j)
#pragma unroll
      for (int r = 0; r < 4; ++r) {
        const int c = w * 32 + 16 * m + quad * 4 + r;
        gpart[(((size_t)l * 64 + b) * 256 + c) * 32 + 16 * j + l16] = acc[m][j][r];
      }
}

// ---------------------------------------------------------------------------
// Head: reduce gpart over l, add g-biases, fc+relu, loc/scale.
// ---------------------------------------------------------------------------
__global__ __launch_bounds__(256) void head_kernel(
    const float* __restrict__ gpart, const float* __restrict__ skip_b,
    const float* __restrict__ fcw, const float* __restrict__ fcb,
    const float* __restrict__ locw, const float* __restrict__ locb,
    const float* __restrict__ scw, const float* __restrict__ scb,
    float* __restrict__ out)
{
  const int tt = blockIdx.x;
  const int b  = blockIdx.y;
  const int c  = threadIdx.x;
  __shared__ float xs[DHID];
  float s = 0.f;
#pragma unroll
  for (int l = 0; l < NLAY; ++l) {
    s += skip_b[l * 512 + 256 + c];
    s += gpart[(((size_t)l * 64 + b) * 256 + c) * 32 + (8 + tt)];
  }
  xs[c] = s;
  __syncthreads();
  float acc = fcb[c];
#pragma unroll 8
  for (int j = 0; j < DHID; ++j) acc = fmaf(xs[j], fcw[j * DHID + c], acc);
  const float ff = fmaxf(acc, 0.f);
  float pl = ff * locw[c];
  float ps = ff * scw[c];
#pragma unroll
  for (int off = 32; off > 0; off >>= 1) {
    pl += __shfl_down(pl, off);
    ps += __shfl_down(ps, off);
  }
  __shared__ float rl[4], rs[4];
  const int wid = threadIdx.x >> 6, lane = threadIdx.x & 63;
  if (lane == 0) { rl[wid] = pl; rs[wid] = ps; }
  __syncthreads();
  if (threadIdx.x == 0) {
    const float loc = rl[0] + rl[1] + rl[2] + rl[3] + locb[0];
    const float x   = rs[0] + rs[1] + rs[2] + rs[3] + scb[0];
    const float sp  = (x > 0.f) ? (x + log1pf(expf(-x))) : log1pf(expf(x));
    out[2 + tt * BB + b]            = loc;
    out[2 + OSL * BB + tt * BB + b] = sp + 1e-6f;
  }
}

__global__ __launch_bounds__(256) void loss_kernel(
    const float* __restrict__ y, float* __restrict__ out)
{
  float s = 0.f;
  for (int i = threadIdx.x; i < OSL * BB; i += 256) {
    const int tt = i >> 6, b = i & 63;
    const float loc = out[2 + i];
    const float sc  = out[2 + OSL * BB + i];
    const float yt  = y[(size_t)(TT - OSL + tt) * BB + b];
    const float z   = (yt - loc) / sc;
    s += -0.5f * z * z - logf(sc) - 0.9189385332046727f;
  }
#pragma unroll
  for (int off = 32; off > 0; off >>= 1) s += __shfl_down(s, off);
  __shared__ float r[4];
  if ((threadIdx.x & 63) == 0) r[threadIdx.x >> 6] = s;
  __syncthreads();
  if (threadIdx.x == 0) {
    const float loss = -(r[0] + r[1] + r[2] + r[3]) / (float)(OSL * BB);
    out[0] = loss;
    out[1] = loss;
  }
}

// ---------------------------------------------------------------------------
extern "C" void kernel_launch(void* const* d_in, const int* in_sizes, int n_in,
                              void* d_out, int out_size, void* d_ws, size_t ws_size,
                              hipStream_t stream) {
  (void)in_sizes; (void)n_in; (void)out_size; (void)ws_size;
  const float* X_cov  = (const float*)d_in[1];
  const float* X_lag  = (const float*)d_in[2];
  const float* y      = (const float*)d_in[3];
  const float* up_w   = (const float*)d_in[5];
  const float* up_b   = (const float*)d_in[6];
  const float* conv_w = (const float*)d_in[7];
  const float* conv_b = (const float*)d_in[8];
  const float* skip_w = (const float*)d_in[9];
  const float* skip_b = (const float*)d_in[10];
  const float* fc_w   = (const float*)d_in[11];
  const float* fc_b   = (const float*)d_in[12];
  const float* loc_w  = (const float*)d_in[13];
  const float* loc_b  = (const float*)d_in[14];
  const float* sc_w   = (const float*)d_in[15];
  const float* sc_b   = (const float*)d_in[16];

  // workspace layout (bytes), total ~122 MB
  char* wsb = (char*)d_ws;
  u16*   hb0   = (u16*)(wsb + 0);            // 27,262,976  [b][32][832][8]
  u16*   hb1   = (u16*)(wsb + 27262976);     // 27,262,976
  u16*   gbuf  = (u16*)(wsb + 54525952);     // 25,165,824  [b][32][768][8]
  u16*   g15   = (u16*)(wsb + 79691776);     // 16,777,216  [l][b][32][64][8]
  u16*   wP    = (u16*)(wsb + 96468992);     //  6,291,456
  u16*   swH   = (u16*)(wsb + 102760448);    //  1,048,576
  u16*   swG   = (u16*)(wsb + 103809024);    //  1,048,576
  float* gpart = (float*)(wsb + 104857600);  // 16,777,216  [l][b][256][32] f32

  wprep<<<1024, 256, 0, stream>>>(conv_w, skip_w, wP, swH, swG);
  up_kernel<<<dim3(52, BB), 256, 0, stream>>>(X_lag, X_cov, up_w, up_b, hb0);

  // minimal t-tiles per layer (receptive-field recurrence, tight at i=5,6,7)
  static const int Ptab[NLAY] = {4, 5, 6, 7, 8, 9, 11, 15};
  u16* hin = hb0;
  u16* hout = hb1;
  for (int i = 0; i < NLAY; ++i) {
    const int ntiles = 16 - Ptab[i];
    conv_gate<<<dim3(ntiles * 32, 2), 512, 0, stream>>>(
        hin, wP + (size_t)i * 393216, conv_b + i * 512, gbuf,
        g15 + (size_t)i * 1048576, 1 << i, Ptab[i]);
    if (i < NLAY - 1) {   // layer 7's h-update is never consumed
      skip_h<<<dim3(ntiles * 32), 512, 0, stream>>>(
          gbuf, swH + (size_t)i * 65536, skip_b + i * 512, hin, hout, Ptab[i]);
      u16* tmp = hin; hin = hout; hout = tmp;
    }
  }

  skip_g<<<dim3(64, 8), 512, 0, stream>>>(g15, swG, gpart);
  head_kernel<<<dim3(OSL, BB), 256, 0, stream>>>(
      gpart, skip_b, fc_w, fc_b, loc_w, loc_b, sc_w, sc_b, (float*)d_out);
  loss_kernel<<<1, 256, 0, stream>>>(y, (float*)d_out);
}